// Round 1
// baseline (146.766 us; speedup 1.0000x reference)
//
#include <hip/hip_runtime.h>

#define HH 128
#define WW 128
#define CC 64
#define CO 64
#define BB 4
#define GG 8
#define CG 8
#define KK 9
#define HW (HH*WW)
#define PXT 64

typedef __attribute__((ext_vector_type(8))) short short8;
typedef __attribute__((ext_vector_type(4))) float floatx4;
typedef __attribute__((ext_vector_type(2))) float f32x2;

union S8I { short8 s; int i[4]; };
union FU { float f; unsigned u; };

__device__ inline short f2bf(float f) {
    FU v; v.f = f;
    return (short)((v.u + 0x7FFF + ((v.u >> 16) & 1)) >> 16);
}
__device__ inline unsigned rnd2(float f) {   // round-half-up bf16 in bits [31:16]
    FU v; v.f = f;
    return v.u + 0x8000u;
}
__device__ inline float bflo(int e) { union { int i; float f; } u; u.i = e << 16; return u.f; }
__device__ inline float bfhi(int e) { union { int i; float f; } u; u.i = e & 0xffff0000; return u.f; }

// ---- merged prep (unchanged) ----
// A-frag layout for the half-K GEMM: fid = (h*9+gc)*4 + ot,
//   wf[fid*512 + L*8 + j] = bf16(W[o=ot*16+(L&15)][g=h*4+(L>>4)][cg=j][kk=gc])
// Input NCHW f32 -> in_t[b][g][y*W+x][cg] bf16 (16B per pixel-group).
__global__ __launch_bounds__(256)
void prep(const float* __restrict__ wt, const float* __restrict__ in,
          short* __restrict__ wf, short* __restrict__ in_t) {
    const int bid = blockIdx.x;
    if (bid < 144) {
        const int tid = bid * 256 + threadIdx.x;   // < 36864 = 576*64
        const int j   = tid & 7;
        const int L   = (tid >> 3) & 63;
        const int fid = tid >> 9;                  // (h*9+gc)*4 + ot, 0..71
        const int ot  = fid & 3;
        const int gch = fid >> 2;                  // h*9 + gc, 0..17
        const int h   = gch / 9, gc = gch - h * 9;
        const int o   = ot * 16 + (L & 15);
        const int g   = h * 4 + (L >> 4);
        wf[tid] = f2bf(wt[o * 576 + (g * 8 + j) * 9 + gc]);
    } else {
        const int idx = bid - 144;                 // 2048 blocks: 64 x 8 x 4
        const int bx = idx & 63;
        const int g  = (idx >> 6) & 7;
        const int b  = idx >> 9;
        const int p  = bx * 256 + threadIdx.x;
        const float* src = in + (b * CC + g * CG) * HW + p;
        short8 v;
        #pragma unroll
        for (int cg = 0; cg < CG; ++cg) v[cg] = f2bf(src[cg * HW]);
        *(short8*)(in_t + ((b * GG + g) * HW + p) * 8) = v;
    }
}

// Barrier-free fused kernel.
// Key identity: the MFMA 16x16x32 B-fragment layout is k=(lane>>4)*8+j, n=lane&15.
// So a lane that gathers all 8 channels of group g=h*4+(lane>>4) at pixel
// px = strip*16 + (lane&15) holds the B-fragment DIRECTLY in its interpolated
// short8 -> no LDS transpose, no __syncthreads, no vmcnt(0) drains. Each of the
// 4 waves per block owns one 16-px strip and free-runs; the compiler can
// pipeline taps and overlap the h=1 offset preload with h=0 MFMAs.
// Grid: 1024 one-D blocks, XCD-swizzled (bid%8 -> contiguous 128-block chunk)
// so each XCD's L2 sees ~64 contiguous ho rows of one image (~1 MB in_t).
__global__ __launch_bounds__(256, 4)
void dcn_fused(const short* __restrict__ in_t, const float* __restrict__ off,
               const float* __restrict__ msk, const short* __restrict__ wf,
               const float* __restrict__ bias, float* __restrict__ out)
{
    // bijective XCD swizzle: 1024 % 8 == 0
    const int lin = (blockIdx.x & 7) * 128 + (blockIdx.x >> 3);
    const int b   = lin >> 8;          // 0..3
    const int rem = lin & 255;
    const int ho  = rem >> 1;          // 0..127
    const int bx  = rem & 1;           // 0..1

    const int t  = threadIdx.x;
    const int w = t >> 6, lane = t & 63;
    const int q4 = lane >> 4, n16 = lane & 15;
    const int px = bx * PXT + w * 16 + n16;       // this lane's output pixel
    const int basepix = ho * WW + px;

    floatx4 acc[4];
    #pragma unroll
    for (int ot = 0; ot < 4; ++ot)
        #pragma unroll
        for (int r = 0; r < 4; ++r)
            acc[ot][r] = bias[ot * 16 + q4 * 4 + r];

    const char* ib = (const char*)(in_t + (long)b * GG * HW * 8);

    #pragma unroll
    for (int h = 0; h < 2; ++h) {
        const int g = h * 4 + q4;      // per-LANE offset group (B-frag k-block)

        // ---- preload off/mask: 27 independent loads, 4x64B lines each ----
        float pdy[9], pdx[9], pm[9];
        #pragma unroll
        for (int i = 0; i < 9; ++i) {
            const int offc = (b * 144 + g * 18 + i * 2) * HW + basepix;
            pdy[i] = off[offc];
            pdx[i] = off[offc + HW];
            pm[i]  = msk[(b * 72 + g * 9 + i) * HW + basepix];
        }

        const int gsh = g << 18;
        #pragma unroll
        for (int i = 0; i < 9; ++i) {
            const int ky = i / 3, kx = i - (i / 3) * 3;   // compile-time consts

            const float py  = (float)(ho - 1 + ky) + pdy[i];
            const float pxf = (float)(px - 1 + kx) + pdx[i];
            const float y0f = floorf(py), x0f = floorf(pxf);
            const float ly = py - y0f, lx = pxf - x0f;
            const int y0 = (int)y0f, x0 = (int)x0f;
            const int y1 = y0 + 1,  x1 = x0 + 1;

            const float vy0 = (y0 >= 0 && y0 < HH) ? 1.f : 0.f;
            const float vy1 = (y1 >= 0 && y1 < HH) ? 1.f : 0.f;
            const float vx0 = (x0 >= 0 && x0 < WW) ? 1.f : 0.f;
            const float vx1 = (x1 >= 0 && x1 < WW) ? 1.f : 0.f;
            const int y0c = min(max(y0, 0), HH - 1), y1c = min(max(y1, 0), HH - 1);
            const int x0c = min(max(x0, 0), WW - 1), x1c = min(max(x1, 0), WW - 1);

            const float m = pm[i];
            const float wy0 = (1.f - ly) * vy0 * m;
            const float wy1 = ly * vy1 * m;
            const float wx0 = (1.f - lx) * vx0;
            const float wx1 = lx * vx1;
            const float w00 = wy0 * wx0, w01 = wy0 * wx1;
            const float w10 = wy1 * wx0, w11 = wy1 * wx1;

            const int y0sh = gsh + (y0c << 11), y1sh = gsh + (y1c << 11);
            const int x0sh = x0c << 4, x1sh = x1c << 4;
            S8I u00, u01, u10, u11;
            u00.s = *(const short8*)(ib + (y0sh + x0sh));
            u01.s = *(const short8*)(ib + (y0sh + x1sh));
            u10.s = *(const short8*)(ib + (y1sh + x0sh));
            u11.s = *(const short8*)(ib + (y1sh + x1sh));

            const f32x2 W00 = {w00, w00}, W01 = {w01, w01};
            const f32x2 W10 = {w10, w10}, W11 = {w11, w11};
            S8I res;
            #pragma unroll
            for (int pc = 0; pc < 4; ++pc) {
                const int e00 = u00.i[pc], e01 = u01.i[pc];
                const int e10 = u10.i[pc], e11 = u11.i[pc];
                f32x2 a00 = {bflo(e00), bfhi(e00)};
                f32x2 a01 = {bflo(e01), bfhi(e01)};
                f32x2 a10 = {bflo(e10), bfhi(e10)};
                f32x2 a11 = {bflo(e11), bfhi(e11)};
                f32x2 v = a00 * W00;
                v += a01 * W01;
                v += a10 * W10;
                v += a11 * W11;
                res.i[pc] = (int)__builtin_amdgcn_perm(rnd2(v.y), rnd2(v.x), 0x07060302u);
            }

            // res.s IS the B-fragment for chunk (h,i): feed MFMA directly.
            #pragma unroll
            for (int ot = 0; ot < 4; ++ot) {
                const short8 afr = *(const short8*)&wf[((h * 9 + i) * 4 + ot) * 512 + lane * 8];
                acc[ot] = __builtin_amdgcn_mfma_f32_16x16x32_bf16(afr, res.s, acc[ot], 0, 0, 0);
            }
        }
    }

    // ---- epilogue: o = ot*16 + q4*4 + r, px as above ----
    #pragma unroll
    for (int ot = 0; ot < 4; ++ot)
        #pragma unroll
        for (int r = 0; r < 4; ++r)
            out[((b * CO + ot * 16 + q4 * 4 + r) * HH + ho) * WW + px] = acc[ot][r];
}

extern "C" void kernel_launch(void* const* d_in, const int* in_sizes, int n_in,
                              void* d_out, int out_size, void* d_ws, size_t ws_size,
                              hipStream_t stream) {
    const float* in   = (const float*)d_in[0];
    const float* off  = (const float*)d_in[1];
    const float* msk  = (const float*)d_in[2];
    const float* wt   = (const float*)d_in[3];
    const float* bias = (const float*)d_in[4];
    float* out = (float*)d_out;
    short* wf   = (short*)d_ws;            // 36864 shorts = 72 KB
    short* in_t = (short*)d_ws + 36864;    // 4*8*16384*8 shorts = 8 MB

    prep<<<144 + 2048, 256, 0, stream>>>(wt, in, wf, in_t);

    dcn_fused<<<1024, 256, 0, stream>>>(in_t, off, msk, wf, bias, out);
}

// Round 3
// 131.054 us; speedup vs baseline: 1.1199x; 1.1199x over previous
//
#include <hip/hip_runtime.h>

#define HH 128
#define WW 128
#define CC 64
#define CO 64
#define BB 4
#define GG 8
#define CG 8
#define KK 9
#define HW (HH*WW)
#define PXT 64

typedef __attribute__((ext_vector_type(8))) short short8;
typedef __attribute__((ext_vector_type(4))) float floatx4;
typedef __attribute__((ext_vector_type(2))) float f32x2;

union S8I { short8 s; int i[4]; };
union FU { float f; unsigned u; };

__device__ inline short f2bf(float f) {
    FU v; v.f = f;
    return (short)((v.u + 0x7FFF + ((v.u >> 16) & 1)) >> 16);
}
__device__ inline unsigned rnd2(float f) {   // round-half-up bf16 in bits [31:16]
    FU v; v.f = f;
    return v.u + 0x8000u;
}
__device__ inline float bflo(int e) { union { int i; float f; } u; u.i = e << 16; return u.f; }
__device__ inline float bfhi(int e) { union { int i; float f; } u; u.i = e & 0xffff0000; return u.f; }

// ---- merged prep (unchanged) ----
// A-frag layout for the half-K GEMM: fid = (h*9+gc)*4 + ot,
//   wf[fid*512 + L*8 + j] = bf16(W[o=ot*16+(L&15)][g=h*4+(L>>4)][cg=j][kk=gc])
// Input NCHW f32 -> in_t[b][g][y*W+x][cg] bf16 (16B per pixel-group).
__global__ __launch_bounds__(256)
void prep(const float* __restrict__ wt, const float* __restrict__ in,
          short* __restrict__ wf, short* __restrict__ in_t) {
    const int bid = blockIdx.x;
    if (bid < 144) {
        const int tid = bid * 256 + threadIdx.x;   // < 36864 = 576*64
        const int j   = tid & 7;
        const int L   = (tid >> 3) & 63;
        const int fid = tid >> 9;                  // (h*9+gc)*4 + ot, 0..71
        const int ot  = fid & 3;
        const int gch = fid >> 2;                  // h*9 + gc, 0..17
        const int h   = gch / 9, gc = gch - h * 9;
        const int o   = ot * 16 + (L & 15);
        const int g   = h * 4 + (L >> 4);
        wf[tid] = f2bf(wt[o * 576 + (g * 8 + j) * 9 + gc]);
    } else {
        const int idx = bid - 144;                 // 2048 blocks: 64 x 8 x 4
        const int bx = idx & 63;
        const int g  = (idx >> 6) & 7;
        const int b  = idx >> 9;
        const int p  = bx * 256 + threadIdx.x;
        const float* src = in + (b * CC + g * CG) * HW + p;
        short8 v;
        #pragma unroll
        for (int cg = 0; cg < CG; ++cg) v[cg] = f2bf(src[cg * HW]);
        *(short8*)(in_t + ((b * GG + g) * HW + p) * 8) = v;
    }
}

// Batched-gather fused kernel, v2b.
// Round-1 lesson: with the A-frag (wf) load inside each tap, the in-order vmcnt
// stream forced a full gather drain per tap -> serialized (VGPR=48, 63us).
// Fix: (a) wf staged in LDS once (lgkmcnt stream, decoupled from gathers);
//      (b) corner loads issued in BATCHES of 5/4 taps (20/16 loads in flight)
//          into statically-indexed register arrays, consumed while the next
//          batch's loads are still in flight. Latency paid ~4x/wave, not 18x.
// Batch split keeps peak gather regs at 80 (vs 144 for all-9) -> no scratch.
__global__ __launch_bounds__(256, 2)
void dcn_fused(const short* __restrict__ in_t, const float* __restrict__ off,
               const float* __restrict__ msk, const short* __restrict__ wf,
               const float* __restrict__ bias, float* __restrict__ out)
{
    __shared__ short s_wf[72 * 512];   // 73728 B: all A-fragments

    const int t  = threadIdx.x;
    // one-shot cooperative copy, contiguous 16B/lane (conflict-free, coalesced)
    #pragma unroll
    for (int k = 0; k < 18; ++k) {
        const int idx = (k * 256 + t) * 8;
        *(short8*)(s_wf + idx) = *(const short8*)(wf + idx);
    }
    __syncthreads();   // only barrier in the kernel

    // bijective XCD swizzle: 1024 % 8 == 0
    const int lin = (blockIdx.x & 7) * 128 + (blockIdx.x >> 3);
    const int b   = lin >> 8;          // 0..3
    const int rem = lin & 255;
    const int ho  = rem >> 1;          // 0..127
    const int bx  = rem & 1;           // 0..1

    const int w = t >> 6, lane = t & 63;
    const int q4 = lane >> 4, n16 = lane & 15;
    const int px = bx * PXT + w * 16 + n16;       // this lane's output pixel
    const int basepix = ho * WW + px;

    floatx4 acc[4];
    #pragma unroll
    for (int ot = 0; ot < 4; ++ot)
        #pragma unroll
        for (int r = 0; r < 4; ++r)
            acc[ot][r] = bias[ot * 16 + q4 * 4 + r];

    const char* ib = (const char*)(in_t + (long)b * GG * HW * 8);

    #pragma unroll
    for (int h = 0; h < 2; ++h) {
        const int g = h * 4 + q4;      // per-LANE offset group (B-frag k-block)

        // ---- preload off/mask: 27 independent fully-coalesced loads ----
        float pdy[9], pdx[9], pm[9];
        #pragma unroll
        for (int i = 0; i < 9; ++i) {
            const int offc = (b * 144 + g * 18 + i * 2) * HW + basepix;
            pdy[i] = off[offc];
            pdx[i] = off[offc + HW];
            pm[i]  = msk[(b * 72 + g * 9 + i) * HW + basepix];
        }

        const int gsh = g << 18;

        // per-batch state: issue loads for taps [i0,i1), then consume while the
        // following batch issues. Static indexing only -> stays in VGPRs.
        S8I u00[5], u01[5], u10[5], u11[5];
        float cw00[5], cw01[5], cw10[5], cw11[5];

        #pragma unroll
        for (int batch = 0; batch < 2; ++batch) {
            const int i0 = batch * 5;
            const int nb = batch ? 4 : 5;

            // ---- issue: addresses + weights + corner loads for this batch ----
            #pragma unroll
            for (int j = 0; j < 5; ++j) {
                if (j >= nb) break;                       // compile-time pruned
                const int i = i0 + j;
                const int ky = i / 3, kx = i - (i / 3) * 3;

                const float py  = (float)(ho - 1 + ky) + pdy[i];
                const float pxf = (float)(px - 1 + kx) + pdx[i];
                const float y0f = floorf(py), x0f = floorf(pxf);
                const float ly = py - y0f, lx = pxf - x0f;
                const int y0 = (int)y0f, x0 = (int)x0f;
                const int y1 = y0 + 1,  x1 = x0 + 1;

                const float vy0 = (y0 >= 0 && y0 < HH) ? 1.f : 0.f;
                const float vy1 = (y1 >= 0 && y1 < HH) ? 1.f : 0.f;
                const float vx0 = (x0 >= 0 && x0 < WW) ? 1.f : 0.f;
                const float vx1 = (x1 >= 0 && x1 < WW) ? 1.f : 0.f;
                const int y0c = min(max(y0, 0), HH - 1), y1c = min(max(y1, 0), HH - 1);
                const int x0c = min(max(x0, 0), WW - 1), x1c = min(max(x1, 0), WW - 1);

                const float m = pm[i];
                const float wy0 = (1.f - ly) * vy0 * m;
                const float wy1 = ly * vy1 * m;
                const float wx0 = (1.f - lx) * vx0;
                const float wx1 = lx * vx1;
                cw00[j] = wy0 * wx0; cw01[j] = wy0 * wx1;
                cw10[j] = wy1 * wx0; cw11[j] = wy1 * wx1;

                const int y0sh = gsh + (y0c << 11), y1sh = gsh + (y1c << 11);
                const int x0sh = x0c << 4, x1sh = x1c << 4;
                u00[j].s = *(const short8*)(ib + (y0sh + x0sh));
                u01[j].s = *(const short8*)(ib + (y0sh + x1sh));
                u10[j].s = *(const short8*)(ib + (y1sh + x0sh));
                u11[j].s = *(const short8*)(ib + (y1sh + x1sh));
            }

            // ---- consume this batch: interp + MFMA; A-frags from LDS ----
            #pragma unroll
            for (int j = 0; j < 5; ++j) {
                if (j >= nb) break;
                const int i = i0 + j;
                const f32x2 W00 = {cw00[j], cw00[j]}, W01 = {cw01[j], cw01[j]};
                const f32x2 W10 = {cw10[j], cw10[j]}, W11 = {cw11[j], cw11[j]};
                S8I res;
                #pragma unroll
                for (int pc = 0; pc < 4; ++pc) {
                    const int e00 = u00[j].i[pc], e01 = u01[j].i[pc];
                    const int e10 = u10[j].i[pc], e11 = u11[j].i[pc];
                    f32x2 a00 = {bflo(e00), bfhi(e00)};
                    f32x2 a01 = {bflo(e01), bfhi(e01)};
                    f32x2 a10 = {bflo(e10), bfhi(e10)};
                    f32x2 a11 = {bflo(e11), bfhi(e11)};
                    f32x2 v = a00 * W00;
                    v += a01 * W01;
                    v += a10 * W10;
                    v += a11 * W11;
                    res.i[pc] = (int)__builtin_amdgcn_perm(rnd2(v.y), rnd2(v.x), 0x07060302u);
                }

                #pragma unroll
                for (int ot = 0; ot < 4; ++ot) {
                    const short8 afr = *(const short8*)&s_wf[((h * 9 + i) * 4 + ot) * 512 + lane * 8];
                    acc[ot] = __builtin_amdgcn_mfma_f32_16x16x32_bf16(afr, res.s, acc[ot], 0, 0, 0);
                }
            }
        }
    }

    // ---- epilogue: o = ot*16 + q4*4 + r, px as above ----
    #pragma unroll
    for (int ot = 0; ot < 4; ++ot)
        #pragma unroll
        for (int r = 0; r < 4; ++r)
            out[((b * CO + ot * 16 + q4 * 4 + r) * HH + ho) * WW + px] = acc[ot][r];
}

extern "C" void kernel_launch(void* const* d_in, const int* in_sizes, int n_in,
                              void* d_out, int out_size, void* d_ws, size_t ws_size,
                              hipStream_t stream) {
    const float* in   = (const float*)d_in[0];
    const float* off  = (const float*)d_in[1];
    const float* msk  = (const float*)d_in[2];
    const float* wt   = (const float*)d_in[3];
    const float* bias = (const float*)d_in[4];
    float* out = (float*)d_out;
    short* wf   = (short*)d_ws;            // 36864 shorts = 72 KB
    short* in_t = (short*)d_ws + 36864;    // 4*8*16384*8 shorts = 8 MB

    prep<<<144 + 2048, 256, 0, stream>>>(wt, in, wf, in_t);

    dcn_fused<<<1024, 256, 0, stream>>>(in_t, off, msk, wf, bias, out);
}